// Round 3
// baseline (1139.200 us; speedup 1.0000x reference)
//
#include <hip/hip_runtime.h>

#define FD 64  // feature dim

static inline long long cdiv_ll(long long a, long long b) { return (a + b - 1) / b; }

// feats[0:na+nb) = concat(a,b); acc_a[0:na) = a; acc_b[0:nb) = b  (all rows x 64)
__global__ void init_concat_kernel(const float* __restrict__ a, const float* __restrict__ b,
                                   int na, int nb,
                                   float* __restrict__ feats,
                                   float* __restrict__ acc_a, float* __restrict__ acc_b) {
    long long idx = (long long)blockIdx.x * blockDim.x + threadIdx.x;
    long long total = (long long)(na + nb) * FD;
    if (idx >= total) return;
    int row = (int)(idx >> 6);
    float v;
    if (row < na) {
        v = a[idx];
        acc_a[idx] = v;
    } else {
        long long j = idx - (long long)na * FD;
        v = b[j];
        acc_b[j] = v;
    }
    feats[idx] = v;
}

// ---------------- CSR build ----------------
__global__ void hist_kernel(const int* __restrict__ rows, int* __restrict__ counts, int nnz) {
    int e = blockIdx.x * blockDim.x + threadIdx.x;
    if (e >= nnz) return;
    atomicAdd(&counts[rows[e]], 1);
}

// single-workgroup chunked exclusive scan: row_ptr[i] = sum(counts[0..i-1]),
// row_ptr[n] = total, cursor[i] = row_ptr[i]
__global__ void scan_kernel(const int* __restrict__ counts, int* __restrict__ row_ptr,
                            int* __restrict__ cursor, int n) {
    __shared__ int sums[1024];
    int tid = threadIdx.x;
    int chunk = (n + 1023) / 1024;
    int start = tid * chunk;
    int end = min(start + chunk, n);
    int s = 0;
    for (int i = start; i < end; ++i) s += counts[i];
    sums[tid] = s;
    __syncthreads();
    for (int o = 1; o < 1024; o <<= 1) {
        int v = 0;
        if (tid >= o) v = sums[tid - o];
        __syncthreads();
        if (tid >= o) sums[tid] += v;
        __syncthreads();
    }
    if (tid == 1023) row_ptr[n] = sums[1023];
    int base = (tid == 0) ? 0 : sums[tid - 1];
    for (int i = start; i < end; ++i) {
        int c = counts[i];
        row_ptr[i] = base;
        cursor[i] = base;
        base += c;
    }
}

__global__ void scatter_kernel(const int* __restrict__ rows, const int* __restrict__ cols,
                               const float* __restrict__ vals, int* __restrict__ cursor,
                               int* __restrict__ scols, float* __restrict__ svals, int nnz) {
    int e = blockIdx.x * blockDim.x + threadIdx.x;
    if (e >= nnz) return;
    int r = rows[e];
    int pos = atomicAdd(&cursor[r], 1);
    scols[pos] = cols[e];
    svals[pos] = vals[e];
}

// ---------------- fused CSR SpMM + L2-normalize-accumulate ----------------
// one wave per row: f = scale * sum_e val*x[col]; feats_out = f;
// acc[row] += f / max(||f||, 1e-12)   (acc split across acc_a / acc_b at `split`)
__global__ void spmm_norm_kernel(const int* __restrict__ row_ptr,
                                 const int* __restrict__ scols, const float* __restrict__ svals,
                                 const float* __restrict__ x, float* __restrict__ feats_out,
                                 float* __restrict__ acc_a, float* __restrict__ acc_b,
                                 int split, int n, float scale) {
    int wave = (int)(((long long)blockIdx.x * blockDim.x + threadIdx.x) >> 6);
    if (wave >= n) return;
    int lane = threadIdx.x & 63;
    int s = row_ptr[wave], e = row_ptr[wave + 1];
    float acc = 0.f;
    for (int j = s; j < e; ++j) {
        int c = scols[j];
        float v = svals[j];
        acc += v * x[(size_t)c * FD + lane];
    }
    acc *= scale;
    feats_out[(size_t)wave * FD + lane] = acc;
    float ss = acc * acc;
#pragma unroll
    for (int o = 32; o >= 1; o >>= 1) ss += __shfl_xor(ss, o);
    float nrm = fmaxf(sqrtf(ss), 1e-12f);
    float add = acc / nrm;
    if (wave < split)
        acc_a[(size_t)wave * FD + lane] += add;
    else
        acc_b[(size_t)(wave - split) * FD + lane] += add;
}

// plain CSR SpMM: y[row] = sum val*x[col]
__global__ void spmm_csr_kernel(const int* __restrict__ row_ptr,
                                const int* __restrict__ scols, const float* __restrict__ svals,
                                const float* __restrict__ x, float* __restrict__ y, int n) {
    int wave = (int)(((long long)blockIdx.x * blockDim.x + threadIdx.x) >> 6);
    if (wave >= n) return;
    int lane = threadIdx.x & 63;
    int s = row_ptr[wave], e = row_ptr[wave + 1];
    float acc = 0.f;
    for (int j = s; j < e; ++j) {
        int c = scols[j];
        float v = svals[j];
        acc += v * x[(size_t)c * FD + lane];
    }
    y[(size_t)wave * FD + lane] = acc;
}

static void build_csr(const int* rows, const int* cols, const float* vals, int nnz, int n,
                      int* counts, int* row_ptr, int* cursor, int* scols, float* svals,
                      hipStream_t stream) {
    hipMemsetAsync(counts, 0, (size_t)n * sizeof(int), stream);
    hist_kernel<<<(int)cdiv_ll(nnz, 256), 256, 0, stream>>>(rows, counts, nnz);
    scan_kernel<<<1, 1024, 0, stream>>>(counts, row_ptr, cursor, n);
    scatter_kernel<<<(int)cdiv_ll(nnz, 256), 256, 0, stream>>>(rows, cols, vals, cursor,
                                                               scols, svals, nnz);
}

extern "C" void kernel_launch(void* const* d_in, const int* in_sizes, int n_in,
                              void* d_out, int out_size, void* d_ws, size_t ws_size,
                              hipStream_t stream) {
    const float* users   = (const float*)d_in[0];
    const float* items   = (const float*)d_in[1];
    const float* bundles = (const float*)d_in[2];
    const int*   il_rows = (const int*)d_in[3];
    const int*   il_cols = (const int*)d_in[4];
    const float* il_vals = (const float*)d_in[5];
    const int*   bl_rows = (const int*)d_in[6];
    const int*   bl_cols = (const int*)d_in[7];
    const float* bl_vals = (const float*)d_in[8];
    const int*   bi_rows = (const int*)d_in[9];
    const int*   bi_cols = (const int*)d_in[10];
    const float* bi_vals = (const float*)d_in[11];

    const int U = in_sizes[0] / FD;   // 50000
    const int I = in_sizes[1] / FD;   // 40000
    const int B = in_sizes[2] / FD;   // 20000
    const int nnz_il = in_sizes[3];   // 1,000,000
    const int nnz_bl = in_sizes[6];   //   600,000
    const int nnz_bi = in_sizes[9];   //   500,000
    const int n1 = U + I;             // 90000
    const int n2 = U + B;             // 70000

    float* out = (float*)d_out;
    // output layout: [il_users (U) | bl_users (U) | il_bundles (B) | bl_bundles (B)] x 64
    float* il_users_acc   = out;
    float* bl_users_acc   = out + (size_t)U * FD;
    float* il_bundles_out = out + (size_t)2 * U * FD;
    float* bl_bundles_acc = out + ((size_t)2 * U + B) * FD;

    // workspace layout (reused CSR region sized for the largest graph: il)
    float* ping      = (float*)d_ws;                       // n1 x 64
    float* pong      = ping + (size_t)n1 * FD;             // n1 x 64
    float* items_acc = pong + (size_t)n1 * FD;             // I x 64
    int*   counts    = (int*)(items_acc + (size_t)I * FD); // n1
    int*   row_ptr   = counts + (n1 + 1);                  // n1 + 1
    int*   cursor    = row_ptr + (n1 + 1);                 // n1
    int*   scols     = cursor + (n1 + 1);                  // nnz_il
    float* svals     = (float*)(scols + nnz_il);           // nnz_il

    const dim3 blk(256);
    const float h = 0.5f, th = 1.0f / 3.0f;
    const int grid_n1 = (int)cdiv_ll((long long)n1 * FD, 256);
    const int grid_n2 = (int)cdiv_ll((long long)n2 * FD, 256);

    // ---------------- item-level propagation (users + items, il graph) ------------
    init_concat_kernel<<<grid_n1, blk, 0, stream>>>(users, items, U, I,
                                                    ping, il_users_acc, items_acc);
    build_csr(il_rows, il_cols, il_vals, nnz_il, n1,
              counts, row_ptr, cursor, scols, svals, stream);
    spmm_norm_kernel<<<grid_n1, blk, 0, stream>>>(row_ptr, scols, svals, ping, pong,
                                                  il_users_acc, items_acc, U, n1, h);
    spmm_norm_kernel<<<grid_n1, blk, 0, stream>>>(row_ptr, scols, svals, pong, ping,
                                                  il_users_acc, items_acc, U, n1, th);

    // bundle aggregation: il_bundles = BI @ il_items_acc (CSR over B rows)
    build_csr(bi_rows, bi_cols, bi_vals, nnz_bi, B,
              counts, row_ptr, cursor, scols, svals, stream);
    spmm_csr_kernel<<<(int)cdiv_ll((long long)B * FD, 256), blk, 0, stream>>>(
        row_ptr, scols, svals, items_acc, il_bundles_out, B);

    // ---------------- bundle-level propagation (users + bundles, bl graph) --------
    init_concat_kernel<<<grid_n2, blk, 0, stream>>>(users, bundles, U, B,
                                                    ping, bl_users_acc, bl_bundles_acc);
    build_csr(bl_rows, bl_cols, bl_vals, nnz_bl, n2,
              counts, row_ptr, cursor, scols, svals, stream);
    spmm_norm_kernel<<<grid_n2, blk, 0, stream>>>(row_ptr, scols, svals, ping, pong,
                                                  bl_users_acc, bl_bundles_acc, U, n2, h);
    spmm_norm_kernel<<<grid_n2, blk, 0, stream>>>(row_ptr, scols, svals, pong, ping,
                                                  bl_users_acc, bl_bundles_acc, U, n2, th);
}

// Round 4
// 794.945 us; speedup vs baseline: 1.4331x; 1.4331x over previous
//
#include <hip/hip_runtime.h>

#define FD 64  // feature dim
#define SCAN_BLOCK 256
#define ELEMS_PER_THREAD 16
#define ELEMS_PER_BLOCK (SCAN_BLOCK * ELEMS_PER_THREAD)  // 4096

static inline long long cdiv_ll(long long a, long long b) { return (a + b - 1) / b; }

// feats[0:na+nb) = concat(a,b); acc_a[0:na) = a; acc_b[0:nb) = b  (all rows x 64)
__global__ void init_concat_kernel(const float* __restrict__ a, const float* __restrict__ b,
                                   int na, int nb,
                                   float* __restrict__ feats,
                                   float* __restrict__ acc_a, float* __restrict__ acc_b) {
    long long idx = (long long)blockIdx.x * blockDim.x + threadIdx.x;
    long long total = (long long)(na + nb) * FD;
    if (idx >= total) return;
    int row = (int)(idx >> 6);
    float v;
    if (row < na) {
        v = a[idx];
        acc_a[idx] = v;
    } else {
        long long j = idx - (long long)na * FD;
        v = b[j];
        acc_b[j] = v;
    }
    feats[idx] = v;
}

// ---------------- CSR build ----------------
__global__ void hist_kernel(const int* __restrict__ rows, int* __restrict__ counts, int nnz) {
    int e = blockIdx.x * blockDim.x + threadIdx.x;
    if (e >= nnz) return;
    atomicAdd(&counts[rows[e]], 1);
}

// pass 1: per-block totals (4096 counts per block)
__global__ void block_sum_kernel(const int* __restrict__ counts, int* __restrict__ block_sums,
                                 int n) {
    int tid = threadIdx.x;
    int base = blockIdx.x * ELEMS_PER_BLOCK + tid * ELEMS_PER_THREAD;
    int s = 0;
#pragma unroll
    for (int i = 0; i < ELEMS_PER_THREAD; ++i) {
        int idx = base + i;
        if (idx < n) s += counts[idx];
    }
    __shared__ int red[SCAN_BLOCK];
    red[tid] = s;
    __syncthreads();
    for (int o = SCAN_BLOCK / 2; o > 0; o >>= 1) {
        if (tid < o) red[tid] += red[tid + o];
        __syncthreads();
    }
    if (tid == 0) block_sums[blockIdx.x] = red[0];
}

// pass 2: exclusive scan of block sums (nb <= 1024) in one block; writes total
__global__ void scan_sums_kernel(int* __restrict__ block_sums, int* __restrict__ total_out,
                                 int nb) {
    __shared__ int sh[1024];
    int tid = threadIdx.x;
    int v = (tid < nb) ? block_sums[tid] : 0;
    sh[tid] = v;
    __syncthreads();
    for (int o = 1; o < 1024; o <<= 1) {
        int t = 0;
        if (tid >= o) t = sh[tid - o];
        __syncthreads();
        sh[tid] += t;
        __syncthreads();
    }
    if (tid < nb) block_sums[tid] = sh[tid] - v;  // exclusive
    if (tid == nb - 1) *total_out = sh[tid];      // grand total -> row_ptr[n]
}

// pass 3: per-block local exclusive scan + block offset -> row_ptr, cursor
__global__ void scan_apply_kernel(const int* __restrict__ counts,
                                  const int* __restrict__ block_sums,
                                  int* __restrict__ row_ptr, int* __restrict__ cursor, int n) {
    int tid = threadIdx.x;
    int base = blockIdx.x * ELEMS_PER_BLOCK + tid * ELEMS_PER_THREAD;
    int local[ELEMS_PER_THREAD];
    int s = 0;
#pragma unroll
    for (int i = 0; i < ELEMS_PER_THREAD; ++i) {
        int idx = base + i;
        int c = (idx < n) ? counts[idx] : 0;
        local[i] = c;
        s += c;
    }
    __shared__ int sh[SCAN_BLOCK];
    sh[tid] = s;
    __syncthreads();
    for (int o = 1; o < SCAN_BLOCK; o <<= 1) {
        int t = 0;
        if (tid >= o) t = sh[tid - o];
        __syncthreads();
        sh[tid] += t;
        __syncthreads();
    }
    int off = block_sums[blockIdx.x] + sh[tid] - s;  // exclusive prefix for this thread
#pragma unroll
    for (int i = 0; i < ELEMS_PER_THREAD; ++i) {
        int idx = base + i;
        if (idx < n) {
            row_ptr[idx] = off;
            cursor[idx] = off;
            off += local[i];
        }
    }
}

__global__ void scatter_kernel(const int* __restrict__ rows, const int* __restrict__ cols,
                               const float* __restrict__ vals, int* __restrict__ cursor,
                               int* __restrict__ scols, float* __restrict__ svals, int nnz) {
    int e = blockIdx.x * blockDim.x + threadIdx.x;
    if (e >= nnz) return;
    int r = rows[e];
    int pos = atomicAdd(&cursor[r], 1);
    scols[pos] = cols[e];
    svals[pos] = vals[e];
}

// ---------------- fused CSR SpMM + L2-normalize-accumulate ----------------
// one wave per row: f = scale * sum_e val*x[col]; feats_out = f;
// acc[row] += f / max(||f||, 1e-12)   (acc split across acc_a / acc_b at `split`)
__global__ void spmm_norm_kernel(const int* __restrict__ row_ptr,
                                 const int* __restrict__ scols, const float* __restrict__ svals,
                                 const float* __restrict__ x, float* __restrict__ feats_out,
                                 float* __restrict__ acc_a, float* __restrict__ acc_b,
                                 int split, int n, float scale) {
    int wave = (int)(((long long)blockIdx.x * blockDim.x + threadIdx.x) >> 6);
    if (wave >= n) return;
    int lane = threadIdx.x & 63;
    int s = row_ptr[wave], e = row_ptr[wave + 1];
    float acc = 0.f;
    for (int j = s; j < e; ++j) {
        int c = scols[j];
        float v = svals[j];
        acc += v * x[(size_t)c * FD + lane];
    }
    acc *= scale;
    feats_out[(size_t)wave * FD + lane] = acc;
    float ss = acc * acc;
#pragma unroll
    for (int o = 32; o >= 1; o >>= 1) ss += __shfl_xor(ss, o);
    float nrm = fmaxf(sqrtf(ss), 1e-12f);
    float add = acc / nrm;
    if (wave < split)
        acc_a[(size_t)wave * FD + lane] += add;
    else
        acc_b[(size_t)(wave - split) * FD + lane] += add;
}

// plain CSR SpMM: y[row] = sum val*x[col]
__global__ void spmm_csr_kernel(const int* __restrict__ row_ptr,
                                const int* __restrict__ scols, const float* __restrict__ svals,
                                const float* __restrict__ x, float* __restrict__ y, int n) {
    int wave = (int)(((long long)blockIdx.x * blockDim.x + threadIdx.x) >> 6);
    if (wave >= n) return;
    int lane = threadIdx.x & 63;
    int s = row_ptr[wave], e = row_ptr[wave + 1];
    float acc = 0.f;
    for (int j = s; j < e; ++j) {
        int c = scols[j];
        float v = svals[j];
        acc += v * x[(size_t)c * FD + lane];
    }
    y[(size_t)wave * FD + lane] = acc;
}

static void build_csr(const int* rows, const int* cols, const float* vals, int nnz, int n,
                      int* counts, int* row_ptr, int* cursor, int* block_sums,
                      int* scols, float* svals, hipStream_t stream) {
    const int nb = (int)cdiv_ll(n, ELEMS_PER_BLOCK);
    hipMemsetAsync(counts, 0, (size_t)n * sizeof(int), stream);
    hist_kernel<<<(int)cdiv_ll(nnz, 256), 256, 0, stream>>>(rows, counts, nnz);
    block_sum_kernel<<<nb, SCAN_BLOCK, 0, stream>>>(counts, block_sums, n);
    scan_sums_kernel<<<1, 1024, 0, stream>>>(block_sums, row_ptr + n, nb);
    scan_apply_kernel<<<nb, SCAN_BLOCK, 0, stream>>>(counts, block_sums, row_ptr, cursor, n);
    scatter_kernel<<<(int)cdiv_ll(nnz, 256), 256, 0, stream>>>(rows, cols, vals, cursor,
                                                               scols, svals, nnz);
}

extern "C" void kernel_launch(void* const* d_in, const int* in_sizes, int n_in,
                              void* d_out, int out_size, void* d_ws, size_t ws_size,
                              hipStream_t stream) {
    const float* users   = (const float*)d_in[0];
    const float* items   = (const float*)d_in[1];
    const float* bundles = (const float*)d_in[2];
    const int*   il_rows = (const int*)d_in[3];
    const int*   il_cols = (const int*)d_in[4];
    const float* il_vals = (const float*)d_in[5];
    const int*   bl_rows = (const int*)d_in[6];
    const int*   bl_cols = (const int*)d_in[7];
    const float* bl_vals = (const float*)d_in[8];
    const int*   bi_rows = (const int*)d_in[9];
    const int*   bi_cols = (const int*)d_in[10];
    const float* bi_vals = (const float*)d_in[11];

    const int U = in_sizes[0] / FD;   // 50000
    const int I = in_sizes[1] / FD;   // 40000
    const int B = in_sizes[2] / FD;   // 20000
    const int nnz_il = in_sizes[3];   // 1,000,000
    const int nnz_bl = in_sizes[6];   //   600,000
    const int nnz_bi = in_sizes[9];   //   500,000
    const int n1 = U + I;             // 90000
    const int n2 = U + B;             // 70000

    float* out = (float*)d_out;
    // output layout: [il_users (U) | bl_users (U) | il_bundles (B) | bl_bundles (B)] x 64
    float* il_users_acc   = out;
    float* bl_users_acc   = out + (size_t)U * FD;
    float* il_bundles_out = out + (size_t)2 * U * FD;
    float* bl_bundles_acc = out + ((size_t)2 * U + B) * FD;

    // workspace layout (reused CSR region sized for the largest graph: il)
    float* ping       = (float*)d_ws;                       // n1 x 64
    float* pong       = ping + (size_t)n1 * FD;             // n1 x 64
    float* items_acc  = pong + (size_t)n1 * FD;             // I x 64
    int*   counts     = (int*)(items_acc + (size_t)I * FD); // n1
    int*   row_ptr    = counts + (n1 + 1);                  // n1 + 1
    int*   cursor     = row_ptr + (n1 + 1);                 // n1
    int*   block_sums = cursor + (n1 + 1);                  // <= 1024
    int*   scols      = block_sums + 1024;                  // nnz_il
    float* svals      = (float*)(scols + nnz_il);           // nnz_il

    const dim3 blk(256);
    const float h = 0.5f, th = 1.0f / 3.0f;
    const int grid_n1 = (int)cdiv_ll((long long)n1 * FD, 256);
    const int grid_n2 = (int)cdiv_ll((long long)n2 * FD, 256);

    // ---------------- item-level propagation (users + items, il graph) ------------
    init_concat_kernel<<<grid_n1, blk, 0, stream>>>(users, items, U, I,
                                                    ping, il_users_acc, items_acc);
    build_csr(il_rows, il_cols, il_vals, nnz_il, n1,
              counts, row_ptr, cursor, block_sums, scols, svals, stream);
    spmm_norm_kernel<<<grid_n1, blk, 0, stream>>>(row_ptr, scols, svals, ping, pong,
                                                  il_users_acc, items_acc, U, n1, h);
    spmm_norm_kernel<<<grid_n1, blk, 0, stream>>>(row_ptr, scols, svals, pong, ping,
                                                  il_users_acc, items_acc, U, n1, th);

    // bundle aggregation: il_bundles = BI @ il_items_acc (CSR over B rows)
    build_csr(bi_rows, bi_cols, bi_vals, nnz_bi, B,
              counts, row_ptr, cursor, block_sums, scols, svals, stream);
    spmm_csr_kernel<<<(int)cdiv_ll((long long)B * FD, 256), blk, 0, stream>>>(
        row_ptr, scols, svals, items_acc, il_bundles_out, B);

    // ---------------- bundle-level propagation (users + bundles, bl graph) --------
    init_concat_kernel<<<grid_n2, blk, 0, stream>>>(users, bundles, U, B,
                                                    ping, bl_users_acc, bl_bundles_acc);
    build_csr(bl_rows, bl_cols, bl_vals, nnz_bl, n2,
              counts, row_ptr, cursor, block_sums, scols, svals, stream);
    spmm_norm_kernel<<<grid_n2, blk, 0, stream>>>(row_ptr, scols, svals, ping, pong,
                                                  bl_users_acc, bl_bundles_acc, U, n2, h);
    spmm_norm_kernel<<<grid_n2, blk, 0, stream>>>(row_ptr, scols, svals, pong, ping,
                                                  bl_users_acc, bl_bundles_acc, U, n2, th);
}

// Round 5
// 637.632 us; speedup vs baseline: 1.7866x; 1.2467x over previous
//
#include <hip/hip_runtime.h>

#define FD 64  // feature dim
#define SCAN_BLOCK 256
#define ELEMS_PER_THREAD 16
#define ELEMS_PER_BLOCK (SCAN_BLOCK * ELEMS_PER_THREAD)  // 4096
#define EDGE_CHUNK 16  // software-pipelined gathers per batch

static inline long long cdiv_ll(long long a, long long b) { return (a + b - 1) / b; }

// feats[0:na+nb) = concat(a,b); acc_a[0:na) = a; acc_b[0:nb) = b  (all rows x 64)
__global__ void init_concat_kernel(const float* __restrict__ a, const float* __restrict__ b,
                                   int na, int nb,
                                   float* __restrict__ feats,
                                   float* __restrict__ acc_a, float* __restrict__ acc_b) {
    long long idx = (long long)blockIdx.x * blockDim.x + threadIdx.x;
    long long total = (long long)(na + nb) * FD;
    if (idx >= total) return;
    int row = (int)(idx >> 6);
    float v;
    if (row < na) {
        v = a[idx];
        acc_a[idx] = v;
    } else {
        long long j = idx - (long long)na * FD;
        v = b[j];
        acc_b[j] = v;
    }
    feats[idx] = v;
}

// ---------------- CSR build ----------------
__global__ void hist_kernel(const int* __restrict__ rows, int* __restrict__ counts, int nnz) {
    int e = blockIdx.x * blockDim.x + threadIdx.x;
    if (e >= nnz) return;
    atomicAdd(&counts[rows[e]], 1);
}

// pass 1: per-block totals (4096 counts per block)
__global__ void block_sum_kernel(const int* __restrict__ counts, int* __restrict__ block_sums,
                                 int n) {
    int tid = threadIdx.x;
    int base = blockIdx.x * ELEMS_PER_BLOCK + tid * ELEMS_PER_THREAD;
    int s = 0;
#pragma unroll
    for (int i = 0; i < ELEMS_PER_THREAD; ++i) {
        int idx = base + i;
        if (idx < n) s += counts[idx];
    }
    __shared__ int red[SCAN_BLOCK];
    red[tid] = s;
    __syncthreads();
    for (int o = SCAN_BLOCK / 2; o > 0; o >>= 1) {
        if (tid < o) red[tid] += red[tid + o];
        __syncthreads();
    }
    if (tid == 0) block_sums[blockIdx.x] = red[0];
}

// pass 2: exclusive scan of block sums (nb <= 1024) in one block; writes total
__global__ void scan_sums_kernel(int* __restrict__ block_sums, int* __restrict__ total_out,
                                 int nb) {
    __shared__ int sh[1024];
    int tid = threadIdx.x;
    int v = (tid < nb) ? block_sums[tid] : 0;
    sh[tid] = v;
    __syncthreads();
    for (int o = 1; o < 1024; o <<= 1) {
        int t = 0;
        if (tid >= o) t = sh[tid - o];
        __syncthreads();
        sh[tid] += t;
        __syncthreads();
    }
    if (tid < nb) block_sums[tid] = sh[tid] - v;  // exclusive
    if (tid == nb - 1) *total_out = sh[tid];      // grand total -> row_ptr[n]
}

// pass 3: per-block local exclusive scan + block offset -> row_ptr, cursor
__global__ void scan_apply_kernel(const int* __restrict__ counts,
                                  const int* __restrict__ block_sums,
                                  int* __restrict__ row_ptr, int* __restrict__ cursor, int n) {
    int tid = threadIdx.x;
    int base = blockIdx.x * ELEMS_PER_BLOCK + tid * ELEMS_PER_THREAD;
    int local[ELEMS_PER_THREAD];
    int s = 0;
#pragma unroll
    for (int i = 0; i < ELEMS_PER_THREAD; ++i) {
        int idx = base + i;
        int c = (idx < n) ? counts[idx] : 0;
        local[i] = c;
        s += c;
    }
    __shared__ int sh[SCAN_BLOCK];
    sh[tid] = s;
    __syncthreads();
    for (int o = 1; o < SCAN_BLOCK; o <<= 1) {
        int t = 0;
        if (tid >= o) t = sh[tid - o];
        __syncthreads();
        sh[tid] += t;
        __syncthreads();
    }
    int off = block_sums[blockIdx.x] + sh[tid] - s;  // exclusive prefix for this thread
#pragma unroll
    for (int i = 0; i < ELEMS_PER_THREAD; ++i) {
        int idx = base + i;
        if (idx < n) {
            row_ptr[idx] = off;
            cursor[idx] = off;
            off += local[i];
        }
    }
}

__global__ void scatter_kernel(const int* __restrict__ rows, const int* __restrict__ cols,
                               const float* __restrict__ vals, int* __restrict__ cursor,
                               int* __restrict__ scols, float* __restrict__ svals, int nnz) {
    int e = blockIdx.x * blockDim.x + threadIdx.x;
    if (e >= nnz) return;
    int r = rows[e];
    int pos = atomicAdd(&cursor[r], 1);
    scols[pos] = cols[e];
    svals[pos] = vals[e];
}

// ---------------- fused CSR SpMM + L2-normalize-accumulate ----------------
// one wave per row, lane = feature dim. Edge loop is software-pipelined in
// chunks of EDGE_CHUNK: load 16 col/val pairs, then issue 16 independent
// gathers (16 VMEM ops in flight instead of 1 dependent chain).
__device__ __forceinline__ float csr_row_gather(const int* __restrict__ row_ptr,
                                                const int* __restrict__ scols,
                                                const float* __restrict__ svals,
                                                const float* __restrict__ x,
                                                int wave, int lane) {
    int s = row_ptr[wave], e = row_ptr[wave + 1];
    float acc = 0.f;
    for (int base = s; base < e; base += EDGE_CHUNK) {
        int   cbuf[EDGE_CHUNK];
        float vbuf[EDGE_CHUNK];
#pragma unroll
        for (int k = 0; k < EDGE_CHUNK; ++k) {
            int idx = base + k;
            int cl = min(idx, e - 1);        // clamp tail (row non-empty here)
            cbuf[k] = scols[cl];
            float vv = svals[cl];
            vbuf[k] = (idx < e) ? vv : 0.f;  // wave-uniform select, unconditional load
        }
#pragma unroll
        for (int k = 0; k < EDGE_CHUNK; ++k)
            acc += vbuf[k] * x[(size_t)cbuf[k] * FD + lane];
    }
    return acc;
}

// f = scale * (A @ x)[row]; feats_out[row] = f; acc[row] += f / max(||f||,1e-12)
__global__ void spmm_norm_kernel(const int* __restrict__ row_ptr,
                                 const int* __restrict__ scols, const float* __restrict__ svals,
                                 const float* __restrict__ x, float* __restrict__ feats_out,
                                 float* __restrict__ acc_a, float* __restrict__ acc_b,
                                 int split, int n, float scale) {
    int wave = (int)(((long long)blockIdx.x * blockDim.x + threadIdx.x) >> 6);
    if (wave >= n) return;
    int lane = threadIdx.x & 63;
    float acc = csr_row_gather(row_ptr, scols, svals, x, wave, lane) * scale;
    feats_out[(size_t)wave * FD + lane] = acc;
    float ss = acc * acc;
#pragma unroll
    for (int o = 32; o >= 1; o >>= 1) ss += __shfl_xor(ss, o);
    float nrm = fmaxf(sqrtf(ss), 1e-12f);
    float add = acc / nrm;
    if (wave < split)
        acc_a[(size_t)wave * FD + lane] += add;
    else
        acc_b[(size_t)(wave - split) * FD + lane] += add;
}

// plain CSR SpMM: y[row] = sum val*x[col]
__global__ void spmm_csr_kernel(const int* __restrict__ row_ptr,
                                const int* __restrict__ scols, const float* __restrict__ svals,
                                const float* __restrict__ x, float* __restrict__ y, int n) {
    int wave = (int)(((long long)blockIdx.x * blockDim.x + threadIdx.x) >> 6);
    if (wave >= n) return;
    int lane = threadIdx.x & 63;
    float acc = csr_row_gather(row_ptr, scols, svals, x, wave, lane);
    y[(size_t)wave * FD + lane] = acc;
}

static void build_csr(const int* rows, const int* cols, const float* vals, int nnz, int n,
                      int* counts, int* row_ptr, int* cursor, int* block_sums,
                      int* scols, float* svals, hipStream_t stream) {
    const int nb = (int)cdiv_ll(n, ELEMS_PER_BLOCK);
    hipMemsetAsync(counts, 0, (size_t)n * sizeof(int), stream);
    hist_kernel<<<(int)cdiv_ll(nnz, 256), 256, 0, stream>>>(rows, counts, nnz);
    block_sum_kernel<<<nb, SCAN_BLOCK, 0, stream>>>(counts, block_sums, n);
    scan_sums_kernel<<<1, 1024, 0, stream>>>(block_sums, row_ptr + n, nb);
    scan_apply_kernel<<<nb, SCAN_BLOCK, 0, stream>>>(counts, block_sums, row_ptr, cursor, n);
    scatter_kernel<<<(int)cdiv_ll(nnz, 256), 256, 0, stream>>>(rows, cols, vals, cursor,
                                                               scols, svals, nnz);
}

extern "C" void kernel_launch(void* const* d_in, const int* in_sizes, int n_in,
                              void* d_out, int out_size, void* d_ws, size_t ws_size,
                              hipStream_t stream) {
    const float* users   = (const float*)d_in[0];
    const float* items   = (const float*)d_in[1];
    const float* bundles = (const float*)d_in[2];
    const int*   il_rows = (const int*)d_in[3];
    const int*   il_cols = (const int*)d_in[4];
    const float* il_vals = (const float*)d_in[5];
    const int*   bl_rows = (const int*)d_in[6];
    const int*   bl_cols = (const int*)d_in[7];
    const float* bl_vals = (const float*)d_in[8];
    const int*   bi_rows = (const int*)d_in[9];
    const int*   bi_cols = (const int*)d_in[10];
    const float* bi_vals = (const float*)d_in[11];

    const int U = in_sizes[0] / FD;   // 50000
    const int I = in_sizes[1] / FD;   // 40000
    const int B = in_sizes[2] / FD;   // 20000
    const int nnz_il = in_sizes[3];   // 1,000,000
    const int nnz_bl = in_sizes[6];   //   600,000
    const int nnz_bi = in_sizes[9];   //   500,000
    const int n1 = U + I;             // 90000
    const int n2 = U + B;             // 70000

    float* out = (float*)d_out;
    // output layout: [il_users (U) | bl_users (U) | il_bundles (B) | bl_bundles (B)] x 64
    float* il_users_acc   = out;
    float* bl_users_acc   = out + (size_t)U * FD;
    float* il_bundles_out = out + (size_t)2 * U * FD;
    float* bl_bundles_acc = out + ((size_t)2 * U + B) * FD;

    // workspace layout (reused CSR region sized for the largest graph: il)
    float* ping       = (float*)d_ws;                       // n1 x 64
    float* pong       = ping + (size_t)n1 * FD;             // n1 x 64
    float* items_acc  = pong + (size_t)n1 * FD;             // I x 64
    int*   counts     = (int*)(items_acc + (size_t)I * FD); // n1
    int*   row_ptr    = counts + (n1 + 1);                  // n1 + 1
    int*   cursor     = row_ptr + (n1 + 1);                 // n1
    int*   block_sums = cursor + (n1 + 1);                  // <= 1024
    int*   scols      = block_sums + 1024;                  // nnz_il
    float* svals      = (float*)(scols + nnz_il);           // nnz_il

    const dim3 blk(256);
    const float h = 0.5f, th = 1.0f / 3.0f;
    const int grid_n1 = (int)cdiv_ll((long long)n1 * FD, 256);
    const int grid_n2 = (int)cdiv_ll((long long)n2 * FD, 256);

    // ---------------- item-level propagation (users + items, il graph) ------------
    init_concat_kernel<<<grid_n1, blk, 0, stream>>>(users, items, U, I,
                                                    ping, il_users_acc, items_acc);
    build_csr(il_rows, il_cols, il_vals, nnz_il, n1,
              counts, row_ptr, cursor, block_sums, scols, svals, stream);
    spmm_norm_kernel<<<grid_n1, blk, 0, stream>>>(row_ptr, scols, svals, ping, pong,
                                                  il_users_acc, items_acc, U, n1, h);
    spmm_norm_kernel<<<grid_n1, blk, 0, stream>>>(row_ptr, scols, svals, pong, ping,
                                                  il_users_acc, items_acc, U, n1, th);

    // bundle aggregation: il_bundles = BI @ il_items_acc (CSR over B rows)
    build_csr(bi_rows, bi_cols, bi_vals, nnz_bi, B,
              counts, row_ptr, cursor, block_sums, scols, svals, stream);
    spmm_csr_kernel<<<(int)cdiv_ll((long long)B * FD, 256), blk, 0, stream>>>(
        row_ptr, scols, svals, items_acc, il_bundles_out, B);

    // ---------------- bundle-level propagation (users + bundles, bl graph) --------
    init_concat_kernel<<<grid_n2, blk, 0, stream>>>(users, bundles, U, B,
                                                    ping, bl_users_acc, bl_bundles_acc);
    build_csr(bl_rows, bl_cols, bl_vals, nnz_bl, n2,
              counts, row_ptr, cursor, block_sums, scols, svals, stream);
    spmm_norm_kernel<<<grid_n2, blk, 0, stream>>>(row_ptr, scols, svals, ping, pong,
                                                  bl_users_acc, bl_bundles_acc, U, n2, h);
    spmm_norm_kernel<<<grid_n2, blk, 0, stream>>>(row_ptr, scols, svals, pong, ping,
                                                  bl_users_acc, bl_bundles_acc, U, n2, th);
}